// Round 1
// baseline (71.005 us; speedup 1.0000x reference)
//
#include <hip/hip_runtime.h>

// ReduceBoundingBoxes NMS — single-launch version.
//   flat[i,c] = X[c*n+i], n = 6400
//   valid = f0 > 0.9 ; b5 = (f0, f1, f0+f2, f1+f3, f4)
//   stable sort valid desc by score; greedy NMS on b5[:,1:5]
//
// Identities (both exact in fp, carried over from the verified 4-kernel
// version):
//  1) rank(i) among valid == #{j valid: sj>si || (sj==si && j<i)}; computing
//     it over the COMPACTED valid set is equivalent, since sj>=si>0.9
//     implies j valid. V ~ 640 here, so V^2 ~ 410K ops << n^2.
//  2) clamped-area==0 boxes have IoU exactly 0 with everything, so greedy
//     NMS == greedy NMS over the positive-area subset only (M ~ 1).
//
// Previous 4-kernel pipeline was dispatch-overhead-bound (~16 us per
// dependent launch; device work per kernel is single-digit us — none of
// our kernels even reached the rocprof top-5). One launch, one block.

#define NTH   1024
#define MAXV  2048   // valid-candidate capacity (V ~ 640 expected)
#define MAXM  256    // positive-area list capacity (M ~ 1 expected)

__global__ __launch_bounds__(NTH, 1) void nms_all(
    const float* __restrict__ X, float* __restrict__ out, int n, int out_n) {
  __shared__ __align__(16) float cscore[MAXV];
  __shared__ unsigned int cidx[MAXV];
  __shared__ int s_vcount, s_mcount, sflag;
  __shared__ int   prank[MAXM];
  __shared__ float pbox[MAXM][4];
  __shared__ float parea[MAXM];
  __shared__ int   srank[MAXM];
  __shared__ float sbox[MAXM][4];
  __shared__ float sarea[MAXM];
  __shared__ int   skeep[MAXM];
  const int t = threadIdx.x;
  if (t == 0) { s_vcount = 0; s_mcount = 0; }

  // ---- issue score loads FIRST (so they aren't queued behind the zero
  //      stores in the per-wave vmcnt FIFO), then the output zeroing ----
  const float4* X4 = (const float4*)X;
  const int n4 = n >> 2;                       // 1600 for n=6400
  float4 sc0 = make_float4(-1.f, -1.f, -1.f, -1.f);
  float4 sc1 = sc0;
  if (t < n4)        sc0 = X4[t];
  if (t + NTH < n4)  sc1 = X4[t + NTH];

  float4* out4 = (float4*)out;
  const int o4 = out_n >> 2;                   // 8000 for out_n=32000
  for (int i = t; i < o4; i += NTH)
    out4[i] = make_float4(0.f, 0.f, 0.f, 0.f);
  for (int i = (o4 << 2) + t; i < out_n; i += NTH) out[i] = 0.f;

  __syncthreads();   // counters visible; zero-stores drained (vmcnt(0))

  // ---- compact valid candidates (score, index) into LDS ----
  if (t < n4) {
    float v[4] = {sc0.x, sc0.y, sc0.z, sc0.w};
    #pragma unroll
    for (int k = 0; k < 4; ++k)
      if (v[k] > 0.9f) {
        int p = atomicAdd(&s_vcount, 1);
        if (p < MAXV) { cscore[p] = v[k]; cidx[p] = (unsigned)(4 * t + k); }
      }
  }
  if (t + NTH < n4) {
    float v[4] = {sc1.x, sc1.y, sc1.z, sc1.w};
    #pragma unroll
    for (int k = 0; k < 4; ++k)
      if (v[k] > 0.9f) {
        int p = atomicAdd(&s_vcount, 1);
        if (p < MAXV) { cscore[p] = v[k]; cidx[p] = (unsigned)(4 * (t + NTH) + k); }
      }
  }
  for (int i = (n4 << 2) + t; i < n; i += NTH) {   // tail (none for n=6400)
    float s = X[i];
    if (s > 0.9f) {
      int p = atomicAdd(&s_vcount, 1);
      if (p < MAXV) { cscore[p] = s; cidx[p] = (unsigned)i; }
    }
  }
  __syncthreads();

  const int V = min(s_vcount, MAXV);
  const int V4 = (V + 3) & ~3;
  for (int e = V + t; e < V4; e += NTH) cscore[e] = -1.f;  // pad: never >, never ==
  __syncthreads();

  // ---- rank each valid entry among valid (float4 LDS sweep), write its
  //      b5 row, and collect positive-area boxes ----
  const float4* c4 = (const float4*)cscore;
  const int nq = V4 >> 2;
  for (int e = t; e < V; e += NTH) {
    float s = cscore[e];
    unsigned idx = cidx[e];
    int gt = 0, eq = 0;
    for (int q = 0; q < nq; ++q) {
      float4 v = c4[q];
      gt += (v.x > s) + (v.y > s) + (v.z > s) + (v.w > s);
      eq += (v.x == s) + (v.y == s) + (v.z == s) + (v.w == s);
    }
    eq -= 1;                     // self is always equal; exclude it
    int rank = gt;
    if (eq > 0) {                // true fp tie: rare; exact fixup
      int lt = 0;
      for (int m = 0; m < V; ++m)
        lt += (cscore[m] == s) && (cidx[m] < idx);
      rank += lt;
    }
    float f1 = X[n + idx], f2 = X[2 * n + idx];
    float f3 = X[3 * n + idx], f4v = X[4 * n + idx];
    float c2 = s + f2, c3 = f1 + f3;             // reference-exact fp
    float* row = out + (size_t)rank * 5;
    row[0] = s; row[1] = f1; row[2] = c2; row[3] = c3; row[4] = f4v;
    // box = (f1, c2, c3, f4); reference-exact area arithmetic:
    float w = fmaxf(c3 - f1, 0.f);
    float h = fmaxf(f4v - c2, 0.f);
    float area = w * h;
    if (area > 0.f) {
      int p = atomicAdd(&s_mcount, 1);
      if (p < MAXM) {
        prank[p] = rank;
        pbox[p][0] = f1; pbox[p][1] = c2; pbox[p][2] = c3; pbox[p][3] = f4v;
        parea[p] = area;
      }
    }
  }
  __syncthreads();

  // ---- sort positive-area boxes by rank (ranks are distinct) ----
  const int M = min(s_mcount, MAXM);
  for (int e = t; e < M; e += NTH) {
    int r = prank[e];
    int pos = 0;
    for (int m = 0; m < M; ++m) pos += (prank[m] < r);
    srank[pos] = r;
    sbox[pos][0] = pbox[e][0]; sbox[pos][1] = pbox[e][1];
    sbox[pos][2] = pbox[e][2]; sbox[pos][3] = pbox[e][3];
    sarea[pos] = parea[e];
    skeep[pos] = 1;
  }
  __syncthreads();

  // ---- greedy NMS (M ~ 1, loop almost never iterates) ----
  for (int i = 1; i < M; ++i) {
    if (t == 0) sflag = 0;
    __syncthreads();
    if (t < i && skeep[t]) {
      float ltx = fmaxf(sbox[t][0], sbox[i][0]);
      float lty = fmaxf(sbox[t][1], sbox[i][1]);
      float rbx = fminf(sbox[t][2], sbox[i][2]);
      float rby = fminf(sbox[t][3], sbox[i][3]);
      float w = fmaxf(rbx - ltx, 0.f);
      float h = fmaxf(rby - lty, 0.f);
      float inter = w * h;
      float uni = sarea[t] + sarea[i] - inter;
      if (inter / fmaxf(uni, 1e-9f) > 0.5f) sflag = 1;
    }
    __syncthreads();
    if (t == 0 && sflag) skeep[i] = 0;
    __syncthreads();
  }

  // ---- zero the suppressed rows ----
  for (int e = t; e < M; e += NTH) {
    if (!skeep[e]) {
      float* row = out + (size_t)srank[e] * 5;
      row[0] = 0.f; row[1] = 0.f; row[2] = 0.f; row[3] = 0.f; row[4] = 0.f;
    }
  }
}

extern "C" void kernel_launch(void* const* d_in, const int* in_sizes, int n_in,
                              void* d_out, int out_size, void* d_ws, size_t ws_size,
                              hipStream_t stream) {
  const float* X = (const float*)d_in[0];
  float* out = (float*)d_out;
  int n = in_sizes[0] / 5;   // 6400
  (void)d_ws; (void)ws_size;
  hipLaunchKernelGGL(nms_all, dim3(1), dim3(NTH), 0, stream, X, out, n, out_size);
}